// Round 20
// baseline (3199.385 us; speedup 1.0000x reference)
//
#include <hip/hip_runtime.h>
#include <hip/hip_fp16.h>
#include <cstdint>
#include <cstddef>

// Sizes (fixed by the problem)
// B=64, T=1024, I=64, H=256, G=3H=768, N=B*T=65536

// Pinned v_dot2_f32_f16: acc += w.h[0]*h.h[0] + w.h[1]*h.h[1]
#define DOT2(acc, w, h) \
    asm("v_dot2_f32_f16 %0, %1, %2, %0" : "+v"(acc) : "v"(w), "v"(h))

// DPP butterfly adds. 0xB1 = quad xor1, 0x4E = quad xor2,
// 0x141 = ROW_HALF_MIRROR (combines the two quads of each 8-lane octet).
template<int CTL>
__device__ __forceinline__ float dpp_add(float x) {
    int t = __builtin_amdgcn_update_dpp(0, __builtin_bit_cast(int, x),
                                        CTL, 0xF, 0xF, true);
    return x + __builtin_bit_cast(float, t);
}

// LDS-only barrier: do NOT drain vmcnt (global loads/stores stay in flight).
__device__ __forceinline__ void lds_barrier() {
    asm volatile("s_waitcnt lgkmcnt(0)\n\ts_barrier" ::: "memory");
}

// Fast transcendentals: raw v_exp (2^x) + v_rcp.
__device__ __forceinline__ float fast_sigmoid(float x) {
    float t = x * -1.4426950408889634f, e, r;
    asm("v_exp_f32 %0, %1" : "=v"(e) : "v"(t));
    float d = 1.f + e;
    asm("v_rcp_f32 %0, %1" : "=v"(r) : "v"(d));
    return r;
}
__device__ __forceinline__ float fast_tanh_clamped(float x) {  // |x| <= 15
    float t = x * 2.8853900817779268f, e, r;                   // 2*log2(e)
    asm("v_exp_f32 %0, %1" : "=v"(e) : "v"(t));
    float d = e + 1.f;
    asm("v_rcp_f32 %0, %1" : "=v"(r) : "v"(d));
    return 1.f - 2.f * r;
}

// Pack w_hh [768][256] f32 -> [768][128] of f16-pairs (adjacent k packed)
__global__ void pack_whh(const float* __restrict__ w1, const float* __restrict__ w2,
                         __half2* __restrict__ o1, __half2* __restrict__ o2) {
    int g = blockIdx.x;       // 0..767
    int k2 = threadIdx.x;     // 0..127
    const float* w = blockIdx.y ? w2 : w1;
    __half2* o = blockIdx.y ? o2 : o1;
    float a = w[g * 256 + 2 * k2];
    float b = w[g * 256 + 2 * k2 + 1];
    o[g * 128 + k2] = __floats2half2_rn(a, b);
}

// xw1 = x[65536,64] @ w_ih1[768,64]^T + b_ih1 -> f16 [65536,768]
__global__ __launch_bounds__(256)
void gemm_xw1(const float* __restrict__ A, const float* __restrict__ W,
              const float* __restrict__ bias, __half* __restrict__ out) {
    __shared__ float As[64][65];
    __shared__ float Ws[64][65];
    const int tid = threadIdx.x;
    const int n0 = blockIdx.y * 64, g0 = blockIdx.x * 64;
    for (int idx = tid; idx < 4096; idx += 256) {
        int r = idx >> 6, c = idx & 63;
        As[r][c] = A[(size_t)(n0 + r) * 64 + c];
        Ws[r][c] = W[(size_t)(g0 + r) * 64 + c];
    }
    __syncthreads();
    const int ty = tid >> 4, tx = tid & 15;
    float acc[4][4] = {};
    for (int k = 0; k < 64; ++k) {
        float a[4], w[4];
        #pragma unroll
        for (int i = 0; i < 4; ++i) a[i] = As[ty * 4 + i][k];
        #pragma unroll
        for (int jj = 0; jj < 4; ++jj) w[jj] = Ws[tx * 4 + jj][k];
        #pragma unroll
        for (int i = 0; i < 4; ++i)
            #pragma unroll
            for (int jj = 0; jj < 4; ++jj) acc[i][jj] += a[i] * w[jj];
    }
    #pragma unroll
    for (int jj = 0; jj < 4; ++jj) {
        float bb = bias[g0 + tx * 4 + jj];
        #pragma unroll
        for (int i = 0; i < 4; ++i)
            out[(size_t)(n0 + ty * 4 + i) * 768 + (g0 + tx * 4 + jj)] =
                __float2half(acc[i][jj] + bb);
    }
}

// xw2 = y1[65536,256](f16) @ w_eff[768,256](f16)^T + b_eff -> f16 [65536,768]
__global__ __launch_bounds__(256)
void gemm_xw2(const __half2* __restrict__ A, const __half2* __restrict__ W,
              const float* __restrict__ bias, __half* __restrict__ out) {
    __shared__ __half2 As[64][33];
    __shared__ __half2 Ws[64][33];
    const int tid = threadIdx.x;
    const int n0 = blockIdx.y * 64, g0 = blockIdx.x * 64;
    const int ty = tid >> 4, tx = tid & 15;
    float acc[4][4] = {};
    for (int kc = 0; kc < 4; ++kc) {
        __syncthreads();
        for (int idx = tid; idx < 2048; idx += 256) {
            int r = idx >> 5, c2 = idx & 31;
            As[r][c2] = A[(size_t)(n0 + r) * 128 + kc * 32 + c2];
            Ws[r][c2] = W[(size_t)(g0 + r) * 128 + kc * 32 + c2];
        }
        __syncthreads();
        #pragma unroll 8
        for (int k2 = 0; k2 < 32; ++k2) {
            unsigned int a2[4], w2[4];
            #pragma unroll
            for (int i = 0; i < 4; ++i)
                a2[i] = __builtin_bit_cast(unsigned int, As[ty * 4 + i][k2]);
            #pragma unroll
            for (int jj = 0; jj < 4; ++jj)
                w2[jj] = __builtin_bit_cast(unsigned int, Ws[tx * 4 + jj][k2]);
            #pragma unroll
            for (int i = 0; i < 4; ++i)
                #pragma unroll
                for (int jj = 0; jj < 4; ++jj)
                    DOT2(acc[i][jj], w2[jj], a2[i]);
        }
    }
    #pragma unroll
    for (int jj = 0; jj < 4; ++jj) {
        float bb = bias[g0 + tx * 4 + jj];
        #pragma unroll
        for (int i = 0; i < 4; ++i)
            out[(size_t)(n0 + ty * 4 + i) * 768 + (g0 + tx * 4 + jj)] =
                __float2half(acc[i][jj] + bb);
    }
}

// GRU recurrence, 2-units x K-EIGHTH partition: 1024 threads/block (16 waves,
// 4 waves/SIMD TLP). thread = (pair p = tid>>3, K-eighth kq = tid&7); owns
// units {2p, 2p+1}. Per-thread weights: 6 rows x 4 uint4 = 96 regs (vs 192 in
// round 19) -> low enough that the allocator VGPR-homes them (no AGPR copy
// per dot, the suspected 60% overhead). Octet reduction: DPP quad xor1 + xor2
// + ROW_HALF_MIRROR (0x141) -- no LDS ops. LDS h: 8 slices of 32 halves
// padded to 80B stride (banks 0,20,8,28,16,4,24,12 -> conflict-free).
template<int LAYER>
__global__ __launch_bounds__(1024, 4)
void rec_kernel(const __half2* __restrict__ wpack,  // [768][128] f16-pairs
                const float* __restrict__ b_hh,     // [768]
                const __half* __restrict__ xw,      // [64][1024][768]
                __half* __restrict__ y_out,         // LAYER==1: [64][1024][256]
                float* __restrict__ stats,          // sum[256], sumsq[256]
                float* __restrict__ mx_out,         // LAYER==2: [64][256]
                float* __restrict__ mn_out) {
    __shared__ __align__(16) uint4 hb4[2][8][5];   // [buf][K-eighth][4 uint4 + pad]
    const int tid = threadIdx.x;   // 0..1023
    const int p   = tid >> 3;      // unit pair 0..127
    const int kq  = tid & 7;       // K-eighth
    const int kql = kq & 1;
    const int u   = 2 * p + kql;   // tail unit this lane finishes (kq<2 active)
    const int b   = blockIdx.x;    // 0..63

    // Weight fragments: rows {2p,2p+1} x gates {r,z,n}, K-eighth kq (4 uint4).
    uint4 Wr0[4], Wr1[4], Wz0[4], Wz1[4], Wn0[4], Wn1[4];
    {
        const uint4* wp4 = (const uint4*)wpack;
        const int mb = kq * 4;
        #pragma unroll
        for (int m = 0; m < 4; ++m) Wr0[m] = wp4[(size_t)(2 * p) * 32 + mb + m];
        #pragma unroll
        for (int m = 0; m < 4; ++m) Wr1[m] = wp4[(size_t)(2 * p + 1) * 32 + mb + m];
        #pragma unroll
        for (int m = 0; m < 4; ++m) Wz0[m] = wp4[(size_t)(2 * p + 256) * 32 + mb + m];
        #pragma unroll
        for (int m = 0; m < 4; ++m) Wz1[m] = wp4[(size_t)(2 * p + 257) * 32 + mb + m];
        #pragma unroll
        for (int m = 0; m < 4; ++m) Wn0[m] = wp4[(size_t)(2 * p + 512) * 32 + mb + m];
        #pragma unroll
        for (int m = 0; m < 4; ++m) Wn1[m] = wp4[(size_t)(2 * p + 513) * 32 + mb + m];
    }

    const float bru = b_hh[u], bzu = b_hh[256 + u], bnu = b_hh[512 + u];

    if (tid < 80) ((uint4*)hb4)[tid] = uint4{0u, 0u, 0u, 0u};  // zero both buffers

    float hprev = 0.f, ssum = 0.f, ssq = 0.f;
    float mx = -3.0e38f, mn = 3.0e38f;
    const __half* xwp = xw + (size_t)b * 1024 * 768;
    __half* yp = (LAYER == 1) ? (y_out + (size_t)b * 1024 * 256) : (__half*)nullptr;

    // prefetch t=0 (lanes kq>=2 mirror kq<2 -- same cachelines)
    __half nxr = xwp[u], nxz = xwp[256 + u], nxn = xwp[512 + u];
    __syncthreads();

    for (int t = 0; t < 1024; ++t) {
        __half cxr = nxr, cxz = nxz, cxn = nxn;
        // prefetch t+1 (t=1023 over-read lands in the adjacent ws region; discarded)
        const __half* xq = xwp + (size_t)(t + 1) * 768;
        nxr = xq[u]; nxz = xq[256 + u]; nxn = xq[512 + u];

        float r0 = 0.f, r1 = 0.f, z0 = 0.f, z1 = 0.f, n0 = 0.f, n1 = 0.f;
        const uint4* hq = hb4[t & 1][kq];
        #pragma unroll
        for (int m = 0; m < 4; ++m) {
            uint4 h = hq[m];
            DOT2(r0, Wr0[m].x, h.x);
            DOT2(r1, Wr1[m].x, h.x);
            DOT2(z0, Wz0[m].x, h.x);
            DOT2(z1, Wz1[m].x, h.x);
            DOT2(n0, Wn0[m].x, h.x);
            DOT2(n1, Wn1[m].x, h.x);
            DOT2(r0, Wr0[m].y, h.y);
            DOT2(r1, Wr1[m].y, h.y);
            DOT2(z0, Wz0[m].y, h.y);
            DOT2(z1, Wz1[m].y, h.y);
            DOT2(n0, Wn0[m].y, h.y);
            DOT2(n1, Wn1[m].y, h.y);
            DOT2(r0, Wr0[m].z, h.z);
            DOT2(r1, Wr1[m].z, h.z);
            DOT2(z0, Wz0[m].z, h.z);
            DOT2(z1, Wz1[m].z, h.z);
            DOT2(n0, Wn0[m].z, h.z);
            DOT2(n1, Wn1[m].z, h.z);
            DOT2(r0, Wr0[m].w, h.w);
            DOT2(r1, Wr1[m].w, h.w);
            DOT2(z0, Wz0[m].w, h.w);
            DOT2(z1, Wz1[m].w, h.w);
            DOT2(n0, Wn0[m].w, h.w);
            DOT2(n1, Wn1[m].w, h.w);
        }
        // octet reduction: quad xor1 + xor2, then half-row mirror joins quads
        r0 = dpp_add<0xB1>(r0); r0 = dpp_add<0x4E>(r0); r0 = dpp_add<0x141>(r0);
        r1 = dpp_add<0xB1>(r1); r1 = dpp_add<0x4E>(r1); r1 = dpp_add<0x141>(r1);
        z0 = dpp_add<0xB1>(z0); z0 = dpp_add<0x4E>(z0); z0 = dpp_add<0x141>(z0);
        z1 = dpp_add<0xB1>(z1); z1 = dpp_add<0x4E>(z1); z1 = dpp_add<0x141>(z1);
        n0 = dpp_add<0xB1>(n0); n0 = dpp_add<0x4E>(n0); n0 = dpp_add<0x141>(n0);
        n1 = dpp_add<0xB1>(n1); n1 = dpp_add<0x4E>(n1); n1 = dpp_add<0x141>(n1);

        float hr = (kql ? r1 : r0) + bru;
        float hz = (kql ? z1 : z0) + bzu;
        float hn = (kql ? n1 : n0) + bnu;

        float xr = __half2float(cxr);
        float xz = __half2float(cxz);
        float xn = __half2float(cxn);
        float r = fast_sigmoid(xr + hr);
        float z = fast_sigmoid(xz + hz);
        float pa = xn + r * hn;
        pa = fminf(fmaxf(pa, -15.f), 15.f);
        float nn = fast_tanh_clamped(pa);
        float h = (1.f - z) * nn + z * hprev;
        hprev = h;
        ssum += h;
        ssq += h * h;
        if (LAYER == 2) { mx = fmaxf(mx, h); mn = fminf(mn, h); }
        __half yh = __float2half(h);
        if (kq < 2) {
            // write h_t for unit u into the other buffer (padded slices: 40
            // halves per slice stride)
            ((__half*)hb4[(t + 1) & 1])[(u >> 5) * 40 + (u & 31)] = yh;
            if (LAYER == 1) yp[(size_t)t * 256 + u] = yh;   // stays in flight
        }
        lds_barrier();   // LDS-only drain: xw loads / y stores not drained
    }
    if (kq < 2) {
        atomicAdd(&stats[u], ssum);
        atomicAdd(&stats[256 + u], ssq);
        if (LAYER == 2) {
            mx_out[b * 256 + u] = mx;
            mn_out[b * 256 + u] = mn;
        }
    }
}

// Fold BN1 (training-mode batch stats) into layer-2 input weights.
__global__ void fold_bn1(const float* __restrict__ w_ih2, const float* __restrict__ b_ih2,
                         const float* __restrict__ g1, const float* __restrict__ be1,
                         const float* __restrict__ stats1,
                         __half* __restrict__ w_eff, float* __restrict__ b_eff) {
    const int g = blockIdx.x, lane = threadIdx.x;  // 768 blocks x 64 threads
    const float invN = 1.f / 65536.f;
    float partial = 0.f;
    for (int c = lane; c < 256; c += 64) {
        float mu = stats1[c] * invN;
        float var = stats1[256 + c] * invN - mu * mu;
        float s = g1[c] * rsqrtf(var + 1e-5f);
        float sh = be1[c] - mu * s;
        float w = w_ih2[g * 256 + c];
        w_eff[g * 256 + c] = __float2half(w * s);
        partial += w * sh;
    }
    #pragma unroll
    for (int off = 32; off > 0; off >>= 1) partial += __shfl_down(partial, off);
    if (lane == 0) b_eff[g] = b_ih2[g] + partial;
}

// BN2 affine -> time max-pool (max if scale>=0 else min) -> tanh -> FC
__global__ void final_kernel(const float* __restrict__ stats2,
                             const float* __restrict__ mx, const float* __restrict__ mn,
                             const float* __restrict__ g2, const float* __restrict__ be2,
                             const float* __restrict__ w_fc, const float* __restrict__ b_fc,
                             float* __restrict__ out) {
    __shared__ float v[256];
    const int b = blockIdx.x, c = threadIdx.x;
    const float invN = 1.f / 65536.f;
    float mu = stats2[c] * invN;
    float var = stats2[256 + c] * invN - mu * mu;
    float s = g2[c] * rsqrtf(var + 1e-5f);
    float d = be2[c] - mu * s;
    float M = (s >= 0.f) ? mx[b * 256 + c] : mn[b * 256 + c];
    v[c] = tanhf(s * M + d);
    __syncthreads();
    if (c < 128) {
        float acc = b_fc[c];
        for (int k = 0; k < 256; ++k) acc += v[k] * w_fc[c * 256 + k];
        out[b * 128 + c] = acc;
    }
}

extern "C" void kernel_launch(void* const* d_in, const int* in_sizes, int n_in,
                              void* d_out, int out_size, void* d_ws, size_t ws_size,
                              hipStream_t stream) {
    const float* x     = (const float*)d_in[0];
    const float* w_ih1 = (const float*)d_in[1];
    const float* w_hh1 = (const float*)d_in[2];
    const float* b_ih1 = (const float*)d_in[3];
    const float* b_hh1 = (const float*)d_in[4];
    const float* g1    = (const float*)d_in[5];
    const float* be1   = (const float*)d_in[6];
    const float* w_ih2 = (const float*)d_in[7];
    const float* w_hh2 = (const float*)d_in[8];
    const float* b_ih2 = (const float*)d_in[9];
    const float* b_hh2 = (const float*)d_in[10];
    const float* g2    = (const float*)d_in[11];
    const float* be2   = (const float*)d_in[12];
    const float* w_fc  = (const float*)d_in[13];
    const float* b_fc  = (const float*)d_in[14];
    float* out = (float*)d_out;

    char* ws = (char*)d_ws;
    size_t off = 0;
    __half*  xw   = (__half*)(ws + off);  off += (size_t)65536 * 768 * 2;  // shared by both layers
    __half*  y1   = (__half*)(ws + off);  off += (size_t)65536 * 256 * 2;
    __half2* wp1  = (__half2*)(ws + off); off += (size_t)768 * 128 * 4;
    __half2* wp2  = (__half2*)(ws + off); off += (size_t)768 * 128 * 4;
    __half*  weff = (__half*)(ws + off);  off += (size_t)768 * 256 * 2;
    float*   beff = (float*)(ws + off);   off += (size_t)768 * 4;
    float*   stats= (float*)(ws + off);   off += (size_t)1024 * 4;         // sum1,sq1,sum2,sq2
    float*   mx2  = (float*)(ws + off);   off += (size_t)64 * 256 * 4;
    float*   mn2  = (float*)(ws + off);   off += (size_t)64 * 256 * 4;

    (void)hipMemsetAsync(stats, 0, 4096, stream);

    pack_whh<<<dim3(768, 2), dim3(128), 0, stream>>>(w_hh1, w_hh2, wp1, wp2);
    gemm_xw1<<<dim3(12, 1024), dim3(256), 0, stream>>>(x, w_ih1, b_ih1, xw);
    rec_kernel<1><<<dim3(64), dim3(1024), 0, stream>>>(wp1, b_hh1, xw, y1, stats,
                                                       (float*)nullptr, (float*)nullptr);
    fold_bn1<<<dim3(768), dim3(64), 0, stream>>>(w_ih2, b_ih2, g1, be1, stats, weff, beff);
    gemm_xw2<<<dim3(12, 1024), dim3(256), 0, stream>>>((const __half2*)y1, (const __half2*)weff,
                                                       beff, xw);
    rec_kernel<2><<<dim3(64), dim3(1024), 0, stream>>>(wp2, b_hh2, xw, (__half*)nullptr,
                                                       stats + 512, mx2, mn2);
    final_kernel<<<dim3(64), dim3(256), 0, stream>>>(stats + 512, mx2, mn2, g2, be2,
                                                     w_fc, b_fc, out);
}

// Round 21
// 2866.920 us; speedup vs baseline: 1.1160x; 1.1160x over previous
//
#include <hip/hip_runtime.h>
#include <hip/hip_fp16.h>
#include <cstdint>
#include <cstddef>

// Sizes (fixed by the problem)
// B=64, T=1024, I=64, H=256, G=3H=768, N=B*T=65536

// Pinned v_dot2_f32_f16: acc += w.h[0]*h.h[0] + w.h[1]*h.h[1]
#define DOT2(acc, w, h) \
    asm("v_dot2_f32_f16 %0, %1, %2, %0" : "+v"(acc) : "v"(w), "v"(h))

// DPP quad-perm butterfly add. 0xB1 = xor1 within quad, 0x4E = xor2.
template<int CTL>
__device__ __forceinline__ float dpp_add(float x) {
    int t = __builtin_amdgcn_update_dpp(0, __builtin_bit_cast(int, x),
                                        CTL, 0xF, 0xF, true);
    return x + __builtin_bit_cast(float, t);
}

// LDS-only barrier: do NOT drain vmcnt (global loads/stores stay in flight).
__device__ __forceinline__ void lds_barrier() {
    asm volatile("s_waitcnt lgkmcnt(0)\n\ts_barrier" ::: "memory");
}

// Fast transcendentals: raw v_exp (2^x) + v_rcp -- avoids the ~10-instr IEEE
// f32 divide expansion of 1/(1+expf(x)). Args bounded (pre-activations
// clamped); rcp ~1e-7 relative, harmless vs f16 storage.
__device__ __forceinline__ float fast_sigmoid(float x) {
    float t = x * -1.4426950408889634f, e, r;
    asm("v_exp_f32 %0, %1" : "=v"(e) : "v"(t));
    float d = 1.f + e;
    asm("v_rcp_f32 %0, %1" : "=v"(r) : "v"(d));
    return r;
}
__device__ __forceinline__ float fast_tanh_clamped(float x) {  // |x| <= 15
    float t = x * 2.8853900817779268f, e, r;                   // 2*log2(e)
    asm("v_exp_f32 %0, %1" : "=v"(e) : "v"(t));                // e^(2x)
    float d = e + 1.f;
    asm("v_rcp_f32 %0, %1" : "=v"(r) : "v"(d));
    return 1.f - 2.f * r;
}

// Pack w_hh [768][256] f32 -> [768][128] of f16-pairs (adjacent k packed)
__global__ void pack_whh(const float* __restrict__ w1, const float* __restrict__ w2,
                         __half2* __restrict__ o1, __half2* __restrict__ o2) {
    int g = blockIdx.x;       // 0..767
    int k2 = threadIdx.x;     // 0..127
    const float* w = blockIdx.y ? w2 : w1;
    __half2* o = blockIdx.y ? o2 : o1;
    float a = w[g * 256 + 2 * k2];
    float b = w[g * 256 + 2 * k2 + 1];
    o[g * 128 + k2] = __floats2half2_rn(a, b);
}

// xw1 = x[65536,64] @ w_ih1[768,64]^T + b_ih1 -> f16 [65536,768]
__global__ __launch_bounds__(256)
void gemm_xw1(const float* __restrict__ A, const float* __restrict__ W,
              const float* __restrict__ bias, __half* __restrict__ out) {
    __shared__ float As[64][65];
    __shared__ float Ws[64][65];
    const int tid = threadIdx.x;
    const int n0 = blockIdx.y * 64, g0 = blockIdx.x * 64;
    for (int idx = tid; idx < 4096; idx += 256) {
        int r = idx >> 6, c = idx & 63;
        As[r][c] = A[(size_t)(n0 + r) * 64 + c];
        Ws[r][c] = W[(size_t)(g0 + r) * 64 + c];
    }
    __syncthreads();
    const int ty = tid >> 4, tx = tid & 15;
    float acc[4][4] = {};
    for (int k = 0; k < 64; ++k) {
        float a[4], w[4];
        #pragma unroll
        for (int i = 0; i < 4; ++i) a[i] = As[ty * 4 + i][k];
        #pragma unroll
        for (int jj = 0; jj < 4; ++jj) w[jj] = Ws[tx * 4 + jj][k];
        #pragma unroll
        for (int i = 0; i < 4; ++i)
            #pragma unroll
            for (int jj = 0; jj < 4; ++jj) acc[i][jj] += a[i] * w[jj];
    }
    #pragma unroll
    for (int jj = 0; jj < 4; ++jj) {
        float bb = bias[g0 + tx * 4 + jj];
        #pragma unroll
        for (int i = 0; i < 4; ++i)
            out[(size_t)(n0 + ty * 4 + i) * 768 + (g0 + tx * 4 + jj)] =
                __float2half(acc[i][jj] + bb);
    }
}

// xw2 = y1[65536,256](f16) @ w_eff[768,256](f16)^T + b_eff -> f16 [65536,768]
__global__ __launch_bounds__(256)
void gemm_xw2(const __half2* __restrict__ A, const __half2* __restrict__ W,
              const float* __restrict__ bias, __half* __restrict__ out) {
    __shared__ __half2 As[64][33];
    __shared__ __half2 Ws[64][33];
    const int tid = threadIdx.x;
    const int n0 = blockIdx.y * 64, g0 = blockIdx.x * 64;
    const int ty = tid >> 4, tx = tid & 15;
    float acc[4][4] = {};
    for (int kc = 0; kc < 4; ++kc) {
        __syncthreads();
        for (int idx = tid; idx < 2048; idx += 256) {
            int r = idx >> 5, c2 = idx & 31;
            As[r][c2] = A[(size_t)(n0 + r) * 128 + kc * 32 + c2];
            Ws[r][c2] = W[(size_t)(g0 + r) * 128 + kc * 32 + c2];
        }
        __syncthreads();
        #pragma unroll 8
        for (int k2 = 0; k2 < 32; ++k2) {
            unsigned int a2[4], w2[4];
            #pragma unroll
            for (int i = 0; i < 4; ++i)
                a2[i] = __builtin_bit_cast(unsigned int, As[ty * 4 + i][k2]);
            #pragma unroll
            for (int jj = 0; jj < 4; ++jj)
                w2[jj] = __builtin_bit_cast(unsigned int, Ws[tx * 4 + jj][k2]);
            #pragma unroll
            for (int i = 0; i < 4; ++i)
                #pragma unroll
                for (int jj = 0; jj < 4; ++jj)
                    DOT2(acc[i][jj], w2[jj], a2[i]);
        }
    }
    #pragma unroll
    for (int jj = 0; jj < 4; ++jj) {
        float bb = bias[g0 + tx * 4 + jj];
        #pragma unroll
        for (int i = 0; i < 4; ++i)
            out[(size_t)(n0 + ty * 4 + i) * 768 + (g0 + tx * 4 + jj)] =
                __float2half(acc[i][jj] + bb);
    }
}

// GRU recurrence, 2-units x K-quarter partition (round-19 config -- the
// measured optimum across partitionings K-split {2,4,8} and MFMA variants):
// 512 threads/block; thread = (pair p = tid>>2, K-quarter kq = tid&3); owns
// units {2p, 2p+1}. 192 weight regs/thread loaded once (AGPR-homed; gfx950
// VALU reads AGPRs natively -- no copy tax). DPP quad butterfly reduction.
// LDS-only barrier keeps global traffic in flight. Fast transcendentals.
template<int LAYER>
__global__ __launch_bounds__(512, 2)
void rec_kernel(const __half2* __restrict__ wpack,  // [768][128] f16-pairs
                const float* __restrict__ b_hh,     // [768]
                const __half* __restrict__ xw,      // [64][1024][768]
                __half* __restrict__ y_out,         // LAYER==1: [64][1024][256]
                float* __restrict__ stats,          // sum[256], sumsq[256]
                float* __restrict__ mx_out,         // LAYER==2: [64][256]
                float* __restrict__ mn_out) {
    __shared__ __align__(16) uint4 hb4[2][4][9];   // [buf][K-quarter][8 uint4 + pad]
    const int tid = threadIdx.x;   // 0..511
    const int p   = tid >> 2;      // unit pair 0..127
    const int kq  = tid & 3;       // K-quarter
    const int kql = kq & 1;
    const int u   = 2 * p + kql;   // tail unit this lane finishes
    const int b   = blockIdx.x;    // 0..63

    // Weight fragments: rows {2p,2p+1} x gates {r,z,n}, K-quarter kq.
    uint4 Wr0[8], Wr1[8], Wz0[8], Wz1[8], Wn0[8], Wn1[8];
    {
        const uint4* wp4 = (const uint4*)wpack;
        const int mb = kq * 8;
        #pragma unroll
        for (int m = 0; m < 8; ++m) Wr0[m] = wp4[(size_t)(2 * p) * 32 + mb + m];
        #pragma unroll
        for (int m = 0; m < 8; ++m) Wr1[m] = wp4[(size_t)(2 * p + 1) * 32 + mb + m];
        #pragma unroll
        for (int m = 0; m < 8; ++m) Wz0[m] = wp4[(size_t)(2 * p + 256) * 32 + mb + m];
        #pragma unroll
        for (int m = 0; m < 8; ++m) Wz1[m] = wp4[(size_t)(2 * p + 257) * 32 + mb + m];
        #pragma unroll
        for (int m = 0; m < 8; ++m) Wn0[m] = wp4[(size_t)(2 * p + 512) * 32 + mb + m];
        #pragma unroll
        for (int m = 0; m < 8; ++m) Wn1[m] = wp4[(size_t)(2 * p + 513) * 32 + mb + m];
    }

    const float bru = b_hh[u], bzu = b_hh[256 + u], bnu = b_hh[512 + u];

    if (tid < 36) ((uint4*)hb4)[tid] = uint4{0u, 0u, 0u, 0u};  // zero buffer 0

    float hprev = 0.f, ssum = 0.f, ssq = 0.f;
    float mx = -3.0e38f, mn = 3.0e38f;
    const __half* xwp = xw + (size_t)b * 1024 * 768;
    __half* yp = (LAYER == 1) ? (y_out + (size_t)b * 1024 * 256) : (__half*)nullptr;

    // prefetch t=0 (lanes kq=2,3 mirror kq=0,1 -- same cacheline)
    __half nxr = xwp[u], nxz = xwp[256 + u], nxn = xwp[512 + u];
    __syncthreads();

    for (int t = 0; t < 1024; ++t) {
        __half cxr = nxr, cxz = nxz, cxn = nxn;
        // prefetch t+1 (t=1023 over-read lands in the adjacent ws region; discarded)
        const __half* xq = xwp + (size_t)(t + 1) * 768;
        nxr = xq[u]; nxz = xq[256 + u]; nxn = xq[512 + u];

        float r0 = 0.f, r1 = 0.f, z0 = 0.f, z1 = 0.f, n0 = 0.f, n1 = 0.f;
        const uint4* hq = hb4[t & 1][kq];
        #pragma unroll
        for (int m = 0; m < 8; ++m) {
            uint4 h = hq[m];
            DOT2(r0, Wr0[m].x, h.x);
            DOT2(r1, Wr1[m].x, h.x);
            DOT2(z0, Wz0[m].x, h.x);
            DOT2(z1, Wz1[m].x, h.x);
            DOT2(n0, Wn0[m].x, h.x);
            DOT2(n1, Wn1[m].x, h.x);
            DOT2(r0, Wr0[m].y, h.y);
            DOT2(r1, Wr1[m].y, h.y);
            DOT2(z0, Wz0[m].y, h.y);
            DOT2(z1, Wz1[m].y, h.y);
            DOT2(n0, Wn0[m].y, h.y);
            DOT2(n1, Wn1[m].y, h.y);
            DOT2(r0, Wr0[m].z, h.z);
            DOT2(r1, Wr1[m].z, h.z);
            DOT2(z0, Wz0[m].z, h.z);
            DOT2(z1, Wz1[m].z, h.z);
            DOT2(n0, Wn0[m].z, h.z);
            DOT2(n1, Wn1[m].z, h.z);
            DOT2(r0, Wr0[m].w, h.w);
            DOT2(r1, Wr1[m].w, h.w);
            DOT2(z0, Wz0[m].w, h.w);
            DOT2(z1, Wz1[m].w, h.w);
            DOT2(n0, Wn0[m].w, h.w);
            DOT2(n1, Wn1[m].w, h.w);
        }
        // combine K-quarters within the 4-lane quad (DPP butterfly, VALU-only)
        r0 = dpp_add<0xB1>(r0); r0 = dpp_add<0x4E>(r0);
        r1 = dpp_add<0xB1>(r1); r1 = dpp_add<0x4E>(r1);
        z0 = dpp_add<0xB1>(z0); z0 = dpp_add<0x4E>(z0);
        z1 = dpp_add<0xB1>(z1); z1 = dpp_add<0x4E>(z1);
        n0 = dpp_add<0xB1>(n0); n0 = dpp_add<0x4E>(n0);
        n1 = dpp_add<0xB1>(n1); n1 = dpp_add<0x4E>(n1);

        float hr = (kql ? r1 : r0) + bru;
        float hz = (kql ? z1 : z0) + bzu;
        float hn = (kql ? n1 : n0) + bnu;

        float xr = __half2float(cxr);
        float xz = __half2float(cxz);
        float xn = __half2float(cxn);
        float r = fast_sigmoid(xr + hr);
        float z = fast_sigmoid(xz + hz);
        float pa = xn + r * hn;
        pa = fminf(fmaxf(pa, -15.f), 15.f);
        float nn = fast_tanh_clamped(pa);
        float h = (1.f - z) * nn + z * hprev;
        hprev = h;
        ssum += h;
        ssq += h * h;
        if (LAYER == 2) { mx = fmaxf(mx, h); mn = fminf(mn, h); }
        __half yh = __float2half(h);
        if (kq < 2) {
            // write h_t for unit u into the other buffer (padded layout)
            ((__half*)hb4[(t + 1) & 1][u >> 6])[u & 63] = yh;
            if (LAYER == 1) yp[(size_t)t * 256 + u] = yh;   // stays in flight
        }
        lds_barrier();   // LDS-only drain: xw loads / y stores not drained
    }
    if (kq < 2) {
        atomicAdd(&stats[u], ssum);
        atomicAdd(&stats[256 + u], ssq);
        if (LAYER == 2) {
            mx_out[b * 256 + u] = mx;
            mn_out[b * 256 + u] = mn;
        }
    }
}

// Fold BN1 (training-mode batch stats) into layer-2 input weights.
__global__ void fold_bn1(const float* __restrict__ w_ih2, const float* __restrict__ b_ih2,
                         const float* __restrict__ g1, const float* __restrict__ be1,
                         const float* __restrict__ stats1,
                         __half* __restrict__ w_eff, float* __restrict__ b_eff) {
    const int g = blockIdx.x, lane = threadIdx.x;  // 768 blocks x 64 threads
    const float invN = 1.f / 65536.f;
    float partial = 0.f;
    for (int c = lane; c < 256; c += 64) {
        float mu = stats1[c] * invN;
        float var = stats1[256 + c] * invN - mu * mu;
        float s = g1[c] * rsqrtf(var + 1e-5f);
        float sh = be1[c] - mu * s;
        float w = w_ih2[g * 256 + c];
        w_eff[g * 256 + c] = __float2half(w * s);
        partial += w * sh;
    }
    #pragma unroll
    for (int off = 32; off > 0; off >>= 1) partial += __shfl_down(partial, off);
    if (lane == 0) b_eff[g] = b_ih2[g] + partial;
}

// BN2 affine -> time max-pool (max if scale>=0 else min) -> tanh -> FC
__global__ void final_kernel(const float* __restrict__ stats2,
                             const float* __restrict__ mx, const float* __restrict__ mn,
                             const float* __restrict__ g2, const float* __restrict__ be2,
                             const float* __restrict__ w_fc, const float* __restrict__ b_fc,
                             float* __restrict__ out) {
    __shared__ float v[256];
    const int b = blockIdx.x, c = threadIdx.x;
    const float invN = 1.f / 65536.f;
    float mu = stats2[c] * invN;
    float var = stats2[256 + c] * invN - mu * mu;
    float s = g2[c] * rsqrtf(var + 1e-5f);
    float d = be2[c] - mu * s;
    float M = (s >= 0.f) ? mx[b * 256 + c] : mn[b * 256 + c];
    v[c] = tanhf(s * M + d);
    __syncthreads();
    if (c < 128) {
        float acc = b_fc[c];
        for (int k = 0; k < 256; ++k) acc += v[k] * w_fc[c * 256 + k];
        out[b * 128 + c] = acc;
    }
}

extern "C" void kernel_launch(void* const* d_in, const int* in_sizes, int n_in,
                              void* d_out, int out_size, void* d_ws, size_t ws_size,
                              hipStream_t stream) {
    const float* x     = (const float*)d_in[0];
    const float* w_ih1 = (const float*)d_in[1];
    const float* w_hh1 = (const float*)d_in[2];
    const float* b_ih1 = (const float*)d_in[3];
    const float* b_hh1 = (const float*)d_in[4];
    const float* g1    = (const float*)d_in[5];
    const float* be1   = (const float*)d_in[6];
    const float* w_ih2 = (const float*)d_in[7];
    const float* w_hh2 = (const float*)d_in[8];
    const float* b_ih2 = (const float*)d_in[9];
    const float* b_hh2 = (const float*)d_in[10];
    const float* g2    = (const float*)d_in[11];
    const float* be2   = (const float*)d_in[12];
    const float* w_fc  = (const float*)d_in[13];
    const float* b_fc  = (const float*)d_in[14];
    float* out = (float*)d_out;

    char* ws = (char*)d_ws;
    size_t off = 0;
    __half*  xw   = (__half*)(ws + off);  off += (size_t)65536 * 768 * 2;  // shared by both layers
    __half*  y1   = (__half*)(ws + off);  off += (size_t)65536 * 256 * 2;
    __half2* wp1  = (__half2*)(ws + off); off += (size_t)768 * 128 * 4;
    __half2* wp2  = (__half2*)(ws + off); off += (size_t)768 * 128 * 4;
    __half*  weff = (__half*)(ws + off);  off += (size_t)768 * 256 * 2;
    float*   beff = (float*)(ws + off);   off += (size_t)768 * 4;
    float*   stats= (float*)(ws + off);   off += (size_t)1024 * 4;         // sum1,sq1,sum2,sq2
    float*   mx2  = (float*)(ws + off);   off += (size_t)64 * 256 * 4;
    float*   mn2  = (float*)(ws + off);   off += (size_t)64 * 256 * 4;

    (void)hipMemsetAsync(stats, 0, 4096, stream);

    pack_whh<<<dim3(768, 2), dim3(128), 0, stream>>>(w_hh1, w_hh2, wp1, wp2);
    gemm_xw1<<<dim3(12, 1024), dim3(256), 0, stream>>>(x, w_ih1, b_ih1, xw);
    rec_kernel<1><<<dim3(64), dim3(512), 0, stream>>>(wp1, b_hh1, xw, y1, stats,
                                                      (float*)nullptr, (float*)nullptr);
    fold_bn1<<<dim3(768), dim3(64), 0, stream>>>(w_ih2, b_ih2, g1, be1, stats, weff, beff);
    gemm_xw2<<<dim3(12, 1024), dim3(256), 0, stream>>>((const __half2*)y1, (const __half2*)weff,
                                                       beff, xw);
    rec_kernel<2><<<dim3(64), dim3(512), 0, stream>>>(wp2, b_hh2, xw, (__half*)nullptr,
                                                      stats + 512, mx2, mn2);
    final_kernel<<<dim3(64), dim3(256), 0, stream>>>(stats + 512, mx2, mn2, g2, be2,
                                                     w_fc, b_fc, out);
}